// Round 1
// baseline (205.030 us; speedup 1.0000x reference)
//
#include <hip/hip_runtime.h>

// Batched dynamic-filter cross-correlation:
// x: [128, 384, 384, 1] f32, k: [128, 8, 8, 1] f32
// out[b,i,j] = sum_{p,q} x[b,i+p,j+q] * k[b,p,q], out: [128, 377, 377, 1]

#define BATCH 128
#define Hh 384
#define Ww 384
#define KH 8
#define KW 8
#define OH 377
#define OW 377

#define TI 32                 // output tile rows per block
#define TJ 64                 // output tile cols per block
#define XR (TI + KH - 1)      // 39 input rows staged
#define XC4 18                // float4 columns loaded per row (72 floats >= 64+15)
#define XS4 19                // padded LDS row stride in float4 (76 floats; 76%32=12 bank rotation)

__global__ __launch_bounds__(256, 2) void corr_kernel(
    const float* __restrict__ x,
    const float* __restrict__ k,
    float* __restrict__ out) {

    __shared__ float4 xs4[XR * XS4];
    __shared__ float  ks[KH * KW];

    const int tj = blockIdx.x;   // 0..5
    const int ti = blockIdx.y;   // 0..11
    const int b  = blockIdx.z;   // 0..127

    const int bi  = ti * TI;
    const int bj  = tj * TJ;
    const int tid = (int)threadIdx.x;

    // ---- stage k (64 floats) ----
    if (tid < 16) {
        ((float4*)ks)[tid] = ((const float4*)(k + (size_t)b * (KH * KW)))[tid];
    }

    // ---- stage x tile: rows bi..bi+38, cols bj..bj+71 (zero-fill OOB) ----
    const float* xb = x + (size_t)b * (Hh * Ww);
    for (int idx = tid; idx < XR * XC4; idx += 256) {
        const int r   = idx / XC4;
        const int c4  = idx - r * XC4;
        const int grow = bi + r;
        const int gcol = bj + c4 * 4;
        float4 v;
        if (grow < Hh && gcol + 3 < Ww) {
            v = *(const float4*)(xb + (size_t)grow * Ww + gcol);
        } else if (grow < Hh) {
            v.x = (gcol + 0 < Ww) ? xb[(size_t)grow * Ww + gcol + 0] : 0.f;
            v.y = (gcol + 1 < Ww) ? xb[(size_t)grow * Ww + gcol + 1] : 0.f;
            v.z = (gcol + 2 < Ww) ? xb[(size_t)grow * Ww + gcol + 2] : 0.f;
            v.w = (gcol + 3 < Ww) ? xb[(size_t)grow * Ww + gcol + 3] : 0.f;
        } else {
            v.x = v.y = v.z = v.w = 0.f;
        }
        xs4[r * XS4 + c4] = v;
    }
    __syncthreads();

    // ---- compute: each thread owns a 1x8 output strip ----
    const int txg = tid & 7;     // j-group 0..7
    const int ty  = tid >> 3;    // output row 0..31
    const int j0  = txg * 8;     // local output col base (multiple of 8 -> b128 aligned)

    float acc[8];
#pragma unroll
    for (int jj = 0; jj < 8; ++jj) acc[jj] = 0.f;

    const float4* ks4 = (const float4*)ks;

#pragma unroll
    for (int p = 0; p < KH; ++p) {
        // kernel row p (wave-uniform broadcast reads)
        float4 k0 = ks4[p * 2 + 0];
        float4 k1 = ks4[p * 2 + 1];
        float kr[8] = {k0.x, k0.y, k0.z, k0.w, k1.x, k1.y, k1.z, k1.w};

        // 16-float input window [j0 .. j0+15] of row ty+p
        const float4* rowp = &xs4[(ty + p) * XS4 + (j0 >> 2)];
        float4 w0 = rowp[0];
        float4 w1 = rowp[1];
        float4 w2 = rowp[2];
        float4 w3 = rowp[3];
        float xw[16] = {w0.x, w0.y, w0.z, w0.w,
                        w1.x, w1.y, w1.z, w1.w,
                        w2.x, w2.y, w2.z, w2.w,
                        w3.x, w3.y, w3.z, w3.w};

#pragma unroll
        for (int q = 0; q < KW; ++q) {
#pragma unroll
            for (int jj = 0; jj < 8; ++jj) {
                acc[jj] = fmaf(xw[q + jj], kr[q], acc[jj]);  // static indices -> registers
            }
        }
    }

    // ---- store (guarded scalar: OW=377 odd, no alignment guarantee) ----
    const int oi = bi + ty;
    if (oi < OH) {
        float* ob = out + ((size_t)b * OH + oi) * OW;
#pragma unroll
        for (int jj = 0; jj < 8; ++jj) {
            const int oj = bj + j0 + jj;
            if (oj < OW) ob[oj] = acc[jj];
        }
    }
}

extern "C" void kernel_launch(void* const* d_in, const int* in_sizes, int n_in,
                              void* d_out, int out_size, void* d_ws, size_t ws_size,
                              hipStream_t stream) {
    const float* x = (const float*)d_in[0];
    const float* k = (const float*)d_in[1];
    float* out = (float*)d_out;

    dim3 grid((OW + TJ - 1) / TJ,   // 6
              (OH + TI - 1) / TI,   // 12
              BATCH);               // 128
    dim3 block(256);
    hipLaunchKernelGGL(corr_kernel, grid, block, 0, stream, x, k, out);
}